// Round 7
// baseline (369.188 us; speedup 1.0000x reference)
//
#include <hip/hip_runtime.h>
#include <hip/hip_bf16.h>

// Problem constants (fixed by reference setup_inputs)
constexpr int BS = 64, C = 256, NH = 4, DH = 64, T = 6, D = 192;
constexpr int HW = 3136;
constexpr int NT = 112;                  // cols per job (7 n-tiles of 16)
constexpr int S = 28;                    // HW splits per (b,h): 28*112 = 3136; one chunk per job
constexpr int PWP = 136;                 // pw row stride (272B; 16B-aligned b128 frags; cols 112-135 zero)
constexpr float SCALE = 0.125f;          // dh^-0.5
constexpr float LN_EPS = 1e-5f;

typedef short bf16x8 __attribute__((ext_vector_type(8)));
typedef float f32x4 __attribute__((ext_vector_type(4)));

__device__ inline unsigned short f2bf(float x) {
    union { float f; unsigned u; } v; v.f = x;
    unsigned r = v.u + 0x7FFFu + ((v.u >> 16) & 1u);   // RNE
    return (unsigned short)(r >> 16);
}

// HW packed convert: 2 f32 -> 2 bf16 in one dword (RNE), gfx950
__device__ inline unsigned cvtpk(float lo, float hi) {
    unsigned d;
    asm("v_cvt_pk_bf16_f32 %0, %1, %2" : "=v"(d) : "v"(lo), "v"(hi));
    return d;
}

__device__ inline bf16x8 pk8f4(float4 a, float4 b) {
    union { unsigned u[4]; bf16x8 v8; } r;
    r.u[0] = cvtpk(a.x, a.y); r.u[1] = cvtpk(a.z, a.w);
    r.u[2] = cvtpk(b.x, b.y); r.u[3] = cvtpk(b.z, b.w);
    return r.v8;
}

__device__ inline bf16x8 pk8(const float* v) {
    union { unsigned u[4]; bf16x8 v8; } r;
    r.u[0] = cvtpk(v[0], v[1]); r.u[1] = cvtpk(v[2], v[3]);
    r.u[2] = cvtpk(v[4], v[5]); r.u[3] = cvtpk(v[6], v[7]);
    return r.v8;
}

__device__ inline void st_bf8(unsigned short* dst, float4 p) {
    *(uint2*)dst = make_uint2(cvtpk(p.x, p.y), cvtpk(p.z, p.w));
}

// ---------------------------------------------------------------------------
// Kernel 1: q = tokens @ q_w^T + q_b ; gate = h_sigmoid(tokens @ alpha_w^T + alpha_b)*2
// 64 blocks: weight rows amortized over all 6 tokens (R1: fusing into the
// split grid de-amortizes weights -> ~1GB L2 traffic, -50us. Keep separate.)
// ---------------------------------------------------------------------------
__global__ __launch_bounds__(256) void qalpha_kernel(
    const float* __restrict__ tokens,   // [T,BS,D]
    const float* __restrict__ q_w,      // [C,D]
    const float* __restrict__ q_b,      // [C]
    const float* __restrict__ alpha_w,  // [C,D]
    const float* __restrict__ alpha_b,  // [C]
    float* __restrict__ q_ws,           // [T,BS,C]
    float* __restrict__ alp_ws)         // [T,BS,C]
{
    int b = blockIdx.x;
    int c = threadIdx.x;
    __shared__ float tok_s[T][D];
    for (int i = c; i < T * (D / 4); i += 256) {
        int t = i / (D / 4), v = i % (D / 4);
        *(float4*)&tok_s[t][4 * v] =
            *(const float4*)&tokens[((size_t)t * BS + b) * D + 4 * v];
    }
    __syncthreads();

    const float4* qr = (const float4*)(q_w + (size_t)c * D);
    const float4* ar = (const float4*)(alpha_w + (size_t)c * D);
    float accq[T] = {0, 0, 0, 0, 0, 0};
    float acca[T] = {0, 0, 0, 0, 0, 0};
    for (int v = 0; v < D / 4; ++v) {
        float4 qw4 = qr[v], aw4 = ar[v];
#pragma unroll
        for (int t = 0; t < T; ++t) {
            float4 t4 = *(const float4*)&tok_s[t][4 * v];
            accq[t] += qw4.x * t4.x + qw4.y * t4.y + qw4.z * t4.z + qw4.w * t4.w;
            acca[t] += aw4.x * t4.x + aw4.y * t4.y + aw4.z * t4.z + aw4.w * t4.w;
        }
    }
    float qb = q_b[c], ab = alpha_b[c];
#pragma unroll
    for (int t = 0; t < T; ++t) {
        size_t idx = ((size_t)t * BS + b) * C + c;
        q_ws[idx] = accq[t] + qb;
        float aa = acca[t] + ab + 3.0f;
        alp_ws[idx] = fminf(fmaxf(aa, 0.0f), 6.0f) * (2.0f / 6.0f);
    }
}

// ---------------------------------------------------------------------------
// Kernel 2: fused attention + mlp — one wave per (b,h,sp) job, NO feature LDS.
// R3-R6 converged to ~85-100us across 4 block structures; the invariant was
// the 64xNT LDS feature tile (>=14KB/job -> <=7 job-pipelines/CU + a serial
// load->cvt->ds_write->gather chain). Here MFMA fragments load DIRECTLY from
// global f32 with full-line coalescing:
//   scores B-frag: lane(col,quad) reads F[quad*8+j][n0+tile*16+col] — per j:
//     4 rows x 16 consecutive floats = 4 full 64B lines per instruction.
//   PV A-frag: 8 consecutive floats of row ct*16+col = 2 aligned float4s
//     (re-read of F; L2/L3-hot, HBM unchanged).
// Softmax is in-register (D-layout row=quad*4+reg -> per-quad 16-lane
// shfl_xor reduce); no online rescale (each job sees its whole slice; merge
// combines local (m,l) exactly as before). Only LDS: pw [16][136] bf16
// (P transposed through LDS + staged mlp_w rows; 4.4KB -> occupancy is
// VGPR-capped at ~16-20 waves/CU, 2-3x more independent streams, 0 barriers).
// ---------------------------------------------------------------------------
__global__ __launch_bounds__(64) void fused_attn_mlp(
    const float* __restrict__ feat,     // [BS,C,HW]
    const float* __restrict__ mlp_w,    // [T,HW]
    const float* __restrict__ q_ws,     // [T,BS,C]
    float* __restrict__ out_attn,       // [BS,NH,T,HW] (pre-softmax scores)
    float* __restrict__ o_part,         // [BS*NH*S][T][DH]
    float* __restrict__ mlp_part,       // [BS*NH*S][T][DH]
    float* __restrict__ ml_part)        // [BS*NH*S][T][2]
{
    int bh = blockIdx.x / S, sp = blockIdx.x % S;
    int b = bh / NH, h = bh % NH;
    int lane = threadIdx.x;
    int col = lane & 15, quad = lane >> 4;
    const int n0 = sp * NT;

    __shared__ unsigned short pw[16][PWP];  // rows 0-5=P, 6-11=W, 12-15=0; cols>=112 zero

    const float* fbase = feat + ((size_t)b * C + h * DH) * HW;

    // ---- one-time zeroes (rows 12-15 whole; cols 112-135 of rows 0-11)
    for (int i = lane; i < 4 * PWP; i += 64) pw[12 + i / PWP][i % PWP] = 0;
    for (int i = lane; i < 12 * 24; i += 64) pw[i / 24][112 + (i % 24)] = 0;
    // ---- stage mlp_w rows (bf16) into pw rows 6-11
    for (int i = lane; i < 6 * (NT / 4); i += 64) {
        int t = i / (NT / 4), v = i % (NT / 4);
        float4 w4 = *(const float4*)&mlp_w[(size_t)t * HW + n0 + 4 * v];
        st_bf8(&pw[6 + t][4 * v], w4);
    }

    // ---- Q A-fragments straight from q_ws (rows t>=6 duplicate row 5; their
    //      score rows are discarded, values finite so no NaN hazard)
    int tq = (col < T) ? col : (T - 1);
    const float* qrow = q_ws + ((size_t)tq * BS + b) * C + h * DH + quad * 8;
    bf16x8 a0 = pk8f4(*(const float4*)&qrow[0],  *(const float4*)&qrow[4]);
    bf16x8 a1 = pk8f4(*(const float4*)&qrow[32], *(const float4*)&qrow[36]);

    // ---- per-row pointers for the scores B-gather (imm offsets tile*64B)
    const float* fcol = fbase + n0 + col;
    const float* rp[8];
    const float* rq[8];
#pragma unroll
    for (int j = 0; j < 8; ++j) {
        rp[j] = fcol + (size_t)(quad * 8 + j) * HW;
        rq[j] = rp[j] + (size_t)32 * HW;
    }

    // ---- scores: 7 tiles of 16 cols, K = 64 (2 x K32 MFMA)
    f32x4 sc[7];
#pragma unroll
    for (int tile = 0; tile < 7; ++tile) {
        float u[8], w[8];
#pragma unroll
        for (int j = 0; j < 8; ++j) { u[j] = rp[j][tile * 16]; w[j] = rq[j][tile * 16]; }
        f32x4 s = {0.f, 0.f, 0.f, 0.f};
        s = __builtin_amdgcn_mfma_f32_16x16x32_bf16(a0, pk8(u), s, 0, 0, 0);
        s = __builtin_amdgcn_mfma_f32_16x16x32_bf16(a1, pk8(w), s, 0, 0, 0);
        s[0] *= SCALE; s[1] *= SCALE; s[2] *= SCALE; s[3] *= SCALE;
        sc[tile] = s;
    }

    // ---- out_attn: pre-softmax scaled scores straight from acc regs
#pragma unroll
    for (int r = 0; r < 4; ++r) {
        int t = quad * 4 + r;
        if (t < T) {
            float* dst = out_attn + ((size_t)bh * T + t) * HW + n0 + col;
#pragma unroll
            for (int tile = 0; tile < 7; ++tile) dst[tile * 16] = sc[tile][r];
        }
    }

    // ---- in-register softmax per score row (16-lane quad reduce), local m/l
#pragma unroll
    for (int r = 0; r < 4; ++r) {
        int t = quad * 4 + r;
        float mx = sc[0][r];
#pragma unroll
        for (int tile = 1; tile < 7; ++tile) mx = fmaxf(mx, sc[tile][r]);
#pragma unroll
        for (int off = 1; off < 16; off <<= 1) mx = fmaxf(mx, __shfl_xor(mx, off));
        float sum = 0.f;
#pragma unroll
        for (int tile = 0; tile < 7; ++tile) {
            float p = __expf(sc[tile][r] - mx);
            sum += p;
            sc[tile][r] = p;
        }
#pragma unroll
        for (int off = 1; off < 16; off <<= 1) sum += __shfl_xor(sum, off);
        if (t < T) {
#pragma unroll
            for (int tile = 0; tile < 7; ++tile)
                pw[t][tile * 16 + col] = f2bf(sc[tile][r]);   // P transpose via LDS
            if (col == 0) {
                ml_part[((size_t)blockIdx.x * T + t) * 2 + 0] = mx;
                ml_part[((size_t)blockIdx.x * T + t) * 2 + 1] = sum;
            }
        }
    }
    // single wave: its own ds_writes are ordered before its ds_reads (lgkmcnt)

    // ---- PV + MLP: D[c][t~] = F x [P;W], K = 128 (cols>=112 zero in pw)
#pragma unroll
    for (int ct = 0; ct < 4; ++ct) {
        f32x4 a = {0.f, 0.f, 0.f, 0.f};
        const float* ar = fbase + (size_t)(ct * 16 + col) * HW;
#pragma unroll
        for (int ks = 0; ks < 4; ++ks) {
            int nn = n0 + ks * 32 + quad * 8;
            if (nn > HW - 8) nn = HW - 8;          // clamp (x0 via pw zeros; avoids OOB)
            bf16x8 af = pk8f4(*(const float4*)&ar[nn], *(const float4*)&ar[nn + 4]);
            bf16x8 bfp = *(const bf16x8*)&pw[col][ks * 32 + quad * 8];
            a = __builtin_amdgcn_mfma_f32_16x16x32_bf16(af, bfp, a, 0, 0, 0);
        }
#pragma unroll
        for (int reg = 0; reg < 4; ++reg) {
            int c2 = ct * 16 + quad * 4 + reg;     // row = channel
            if (col < 6) {
                o_part[((size_t)blockIdx.x * T + col) * DH + c2] = a[reg];
            } else if (col < 12) {
                mlp_part[((size_t)blockIdx.x * T + (col - 6)) * DH + c2] = a[reg];
            }
        }
    }
}

// ---------------------------------------------------------------------------
// Kernel 3: merge split partials + gate + proj + residual + LayerNorm.
// S=28 now: two-pass (M, then weighted sums) with L2-hot re-reads of ml_part
// to avoid 56-VGPR m/l arrays.
// ---------------------------------------------------------------------------
__global__ __launch_bounds__(256) void merge_proj_ln_kernel(
    const float* __restrict__ o_part,
    const float* __restrict__ mlp_part,
    const float* __restrict__ ml_part,
    const float* __restrict__ mlp_b,    // [T]
    const float* __restrict__ alp_ws,   // [T,BS,C]
    const float* __restrict__ tokens,   // [T,BS,D]
    const float* __restrict__ proj_w,   // [D,C]
    const float* __restrict__ proj_b,   // [D]
    const float* __restrict__ ln_g,     // [D]
    const float* __restrict__ ln_b,     // [D]
    float* __restrict__ out_tok)        // [T,BS,D]
{
    int tb = blockIdx.x;
    int t = tb / BS, b = tb % BS;
    int tid = threadIdx.x;
    __shared__ float g_s[C];
    __shared__ float r1[4], r2[4];

    {
        int c = tid;
        int h = c >> 6, cl = c & 63;
        int bh = b * NH + h;
        float M = -3e38f;
        for (int s2 = 0; s2 < S; ++s2)
            M = fmaxf(M, ml_part[((size_t)(bh * S + s2) * T + t) * 2 + 0]);
        float L = 0.f, O = 0.f, MLP = 0.f;
        for (int s2 = 0; s2 < S; ++s2) {
            size_t blk = (size_t)(bh * S + s2);
            float m = ml_part[(blk * T + t) * 2 + 0];
            float l = ml_part[(blk * T + t) * 2 + 1];
            float w = __expf(m - M);
            size_t pidx = (blk * T + t) * DH + cl;
            L += l * w;
            O += o_part[pidx] * w;
            MLP += mlp_part[pidx];
        }
        size_t idx = (size_t)tb * C + c;
        g_s[c] = (MLP + mlp_b[t] + O / L) * alp_ws[idx];
    }
    __syncthreads();

    if (tid < D) {
        int d = tid;
        float acc = proj_b[d] + tokens[(size_t)tb * D + d];
        const float4* pr = (const float4*)(proj_w + (size_t)d * C);
#pragma unroll 8
        for (int v = 0; v < C / 4; ++v) {
            float4 w4 = pr[v];
            float4 g4 = *(const float4*)&g_s[4 * v];
            acc += w4.x * g4.x + w4.y * g4.y + w4.z * g4.z + w4.w * g4.w;
        }

        float s1 = acc, s2 = acc * acc;
#pragma unroll
        for (int off = 32; off; off >>= 1) { s1 += __shfl_down(s1, off); s2 += __shfl_down(s2, off); }
        int wv = d >> 6, lane = d & 63;
        if (lane == 0) { r1[wv] = s1; r2[wv] = s2; }
        __syncthreads();
        float sum1 = r1[0] + r1[1] + r1[2];
        float sum2 = r2[0] + r2[1] + r2[2];
        float mu = sum1 * (1.0f / D);
        float var = sum2 * (1.0f / D) - mu * mu;
        float inv = rsqrtf(var + LN_EPS);
        out_tok[(size_t)tb * D + d] = (acc - mu) * inv * ln_g[d] + ln_b[d];
    } else {
        __syncthreads();
    }
}

// ---------------------------------------------------------------------------
extern "C" void kernel_launch(void* const* d_in, const int* in_sizes, int n_in,
                              void* d_out, int out_size, void* d_ws, size_t ws_size,
                              hipStream_t stream) {
    const float* features = (const float*)d_in[0];
    const float* tokens   = (const float*)d_in[1];
    const float* mlp_w    = (const float*)d_in[2];
    const float* mlp_b    = (const float*)d_in[3];
    const float* q_w      = (const float*)d_in[4];
    const float* q_b      = (const float*)d_in[5];
    const float* alpha_w  = (const float*)d_in[6];
    const float* alpha_b  = (const float*)d_in[7];
    const float* proj_w   = (const float*)d_in[8];
    const float* proj_b   = (const float*)d_in[9];
    const float* ln_g     = (const float*)d_in[10];
    const float* ln_b     = (const float*)d_in[11];

    float* out_tok  = (float*)d_out;                   // [T,BS,D]
    float* out_attn = (float*)d_out + T * BS * D;      // [BS,NH,T,HW]

    constexpr int NBLK = BS * NH * S;                  // 7168
    float* q_ws     = (float*)d_ws;                    // T*BS*C
    float* alp_ws   = q_ws + T * BS * C;               // T*BS*C
    float* ml_part  = alp_ws + T * BS * C;             // NBLK*T*2
    float* o_part   = ml_part + NBLK * T * 2;          // NBLK*T*DH
    float* mlp_part = o_part + NBLK * T * DH;          // NBLK*T*DH

    qalpha_kernel<<<BS, 256, 0, stream>>>(
        tokens, q_w, q_b, alpha_w, alpha_b, q_ws, alp_ws);

    fused_attn_mlp<<<NBLK, 64, 0, stream>>>(
        features, mlp_w, q_ws, out_attn, o_part, mlp_part, ml_part);

    merge_proj_ln_kernel<<<T * BS, 256, 0, stream>>>(
        o_part, mlp_part, ml_part, mlp_b, alp_ws, tokens,
        proj_w, proj_b, ln_g, ln_b, out_tok);
}